// Round 1
// baseline (790.615 us; speedup 1.0000x reference)
//
#include <hip/hip_runtime.h>
#include <hip/hip_bf16.h>
#include <stdint.h>

#define Bb 2
#define Ss 2048
#define Hh 4096
#define NHh 32
#define HDd 128
#define KVHh 2

typedef __attribute__((ext_vector_type(8))) short bf16x8;
typedef __attribute__((ext_vector_type(4))) float f32x4;
typedef unsigned short u16;
typedef unsigned int u32;
typedef unsigned long long u64;

__device__ __forceinline__ u16 f2b(float f) {
  union { float f; u32 u; } v; v.f = f;
  u32 r = v.u + 0x7fffu + ((v.u >> 16) & 1u);
  return (u16)(r >> 16);
}
__device__ __forceinline__ float b2f(u16 h) {
  union { u32 u; float f; } v; v.u = ((u32)h) << 16;
  return v.f;
}

// async global->LDS, 16B per lane; LDS dest is wave-uniform base + lane*16
__device__ __forceinline__ void gload_lds16(const u16* g, u16* l) {
  __builtin_amdgcn_global_load_lds(
      (const __attribute__((address_space(1))) u32*)(uintptr_t)g,
      (__attribute__((address_space(3))) u32*)(u32)(uintptr_t)l,
      16, 0, 0);
}

// ---------------- f32 -> bf16 convert (vectorized) ----------------
__global__ void cvt_k(const float* __restrict__ in, u16* __restrict__ out, int n) {
  int i = blockIdx.x * blockDim.x + threadIdx.x;
  int idx = i * 4;
  if (idx >= n) return;
  float4 v = *(const float4*)&in[idx];
  u64 pack = (u64)f2b(v.x) | ((u64)f2b(v.y) << 16) |
             ((u64)f2b(v.z) << 32) | ((u64)f2b(v.w) << 48);
  *(u64*)&out[idx] = pack;
}

// ---------------- RoPE in-place on (B, nheads, S, HD) bf16 ----------------
__global__ void rope_k(u16* __restrict__ X, const float* __restrict__ rope, int nheads) {
  int i = blockIdx.x * blockDim.x + threadIdx.x;
  int p = i & 31;                  // rotary pair index 0..31
  int s = (i >> 5) & (Ss - 1);
  int bh = i >> 16;                // S*32 == 1<<16
  if (bh >= Bb * nheads) return;
  int b = bh / nheads;
  size_t base = ((size_t)bh * Ss + s) * HDd + p * 2;
  u32 x01 = *(u32*)&X[base];
  float x0 = b2f((u16)(x01 & 0xffff));
  float x1 = b2f((u16)(x01 >> 16));
  float2 rc = *(const float2*)&rope[(((size_t)b * Ss + s) * 32 + p) * 2];
  float o0 = x0 * rc.x - x1 * rc.y;
  float o1 = x1 * rc.x + x0 * rc.y;
  u32 o = (u32)f2b(o0) | ((u32)f2b(o1) << 16);
  *(u32*)&X[base] = o;
}

// ---------------- 128x128 tile GEMM, C = A * B^T (both K-major) ----------------
// EPI=0: plain f32 store to Cout. EPI=1: +bias, scatter bf16 into Q/K/V layouts.
template <int EPI>
__global__ void gemm_bt(const u16* __restrict__ A, const u16* __restrict__ Bm,
                        int M, int N, int K,
                        float* __restrict__ Cout, const float* __restrict__ bias,
                        u16* __restrict__ Qb, u16* __restrict__ Kb, u16* __restrict__ Vb) {
  __shared__ u16 As[128 * 32];
  __shared__ u16 Bs[128 * 32];
  const int tid = threadIdx.x;
  const int wave = tid >> 6;
  const int lane = tid & 63;
  const int lr = lane & 15;
  const int lk = lane >> 4;
  const int wr = wave >> 1;
  const int wc = wave & 1;
  const int m0 = blockIdx.y * 128;
  const int n0 = blockIdx.x * 128;
  const int sa_row = lane >> 2;   // 0..15 within 16-row slot
  const int sa_cb = lane & 3;     // 16B chunk within 64B row

  f32x4 acc[4][4];
#pragma unroll
  for (int i = 0; i < 4; ++i)
#pragma unroll
    for (int j = 0; j < 4; ++j) acc[i][j] = (f32x4){0.f, 0.f, 0.f, 0.f};

  for (int k0 = 0; k0 < K; k0 += 32) {
    __syncthreads();
#pragma unroll
    for (int i = 0; i < 2; ++i) {
      int slot = wave * 2 + i;
      int row = slot * 16 + sa_row;
      gload_lds16(A + (size_t)(m0 + row) * K + k0 + sa_cb * 8, &As[slot * 512]);
      gload_lds16(Bm + (size_t)(n0 + row) * K + k0 + sa_cb * 8, &Bs[slot * 512]);
    }
    __syncthreads();
    bf16x8 af[4], bf[4];
#pragma unroll
    for (int mi = 0; mi < 4; ++mi)
      af[mi] = *(const bf16x8*)&As[(wr * 64 + mi * 16 + lr) * 32 + lk * 8];
#pragma unroll
    for (int ni = 0; ni < 4; ++ni)
      bf[ni] = *(const bf16x8*)&Bs[(wc * 64 + ni * 16 + lr) * 32 + lk * 8];
#pragma unroll
    for (int mi = 0; mi < 4; ++mi)
#pragma unroll
      for (int ni = 0; ni < 4; ++ni)
        acc[mi][ni] = __builtin_amdgcn_mfma_f32_16x16x32_bf16(af[mi], bf[ni], acc[mi][ni], 0, 0, 0);
  }

  if constexpr (EPI == 0) {
#pragma unroll
    for (int mi = 0; mi < 4; ++mi)
#pragma unroll
      for (int ni = 0; ni < 4; ++ni) {
        int col = n0 + wc * 64 + ni * 16 + lr;
        int rowb = m0 + wr * 64 + mi * 16 + lk * 4;
#pragma unroll
        for (int j = 0; j < 4; ++j)
          Cout[(size_t)(rowb + j) * N + col] = acc[mi][ni][j];
      }
  } else {
#pragma unroll
    for (int ni = 0; ni < 4; ++ni) {
      int n = n0 + wc * 64 + ni * 16 + lr;
      float bv = bias[n];
#pragma unroll
      for (int mi = 0; mi < 4; ++mi) {
        int mb = m0 + wr * 64 + mi * 16 + lk * 4;
#pragma unroll
        for (int j = 0; j < 4; ++j) {
          int m = mb + j;
          int bb = m >> 11;        // / 2048
          int ss = m & 2047;
          u16 hv = f2b(acc[mi][ni][j] + bv);
          if (n < 4096) {
            Qb[(((size_t)bb * NHh + (n >> 7)) * Ss + ss) * HDd + (n & 127)] = hv;
          } else if (n < 4352) {
            int idx = n - 4096;
            Kb[(((size_t)bb * KVHh + (idx >> 7)) * Ss + ss) * HDd + (idx & 127)] = hv;
          } else {
            int idx = n - 4352;
            Vb[(((size_t)bb * KVHh + (idx >> 7)) * Ss + ss) * HDd + (idx & 127)] = hv;
          }
        }
      }
    }
  }
}

// ---------------- causal GQA flash attention ----------------
// grid (S/64, NH, B); 256 threads = 4 waves; wave w owns q rows qs+w*16..+16
__global__ void attn_k(const u16* __restrict__ Qb, const u16* __restrict__ Kb,
                       const u16* __restrict__ Vb, u16* __restrict__ Ctx) {
  __shared__ u16 Kt[64 * 128];      // [kv][d], chunk-swizzled: p = (c&8)|((c^kv)&7)
  __shared__ u16 Vt[128 * 64];      // [d][kv] transposed, p = c ^ (d&7)
  __shared__ u16 Pw[4][16 * 64];    // per-wave P [q][kv], p = c ^ (q&7)
  const int tid = threadIdx.x;
  const int w = tid >> 6;
  const int lane = tid & 63;
  const int lr = lane & 15;
  const int lk = lane >> 4;
  const int qt = blockIdx.x, h = blockIdx.y, b = blockIdx.z;
  const int qs = qt * 64;
  const int hkv = h >> 4;           // rep = NH/KVH = 16
  const u16* Qp = Qb + ((size_t)(b * NHh + h)) * Ss * HDd;
  const u16* Kp = Kb + ((size_t)(b * KVHh + hkv)) * Ss * HDd;
  const u16* Vp = Vb + ((size_t)(b * KVHh + hkv)) * Ss * HDd;

  const int qrow = qs + w * 16 + lr;
  bf16x8 qf[4];
#pragma unroll
  for (int kb = 0; kb < 4; ++kb)
    qf[kb] = *(const bf16x8*)&Qp[(size_t)qrow * HDd + kb * 32 + lk * 8];

  float m_r[4], l_r[4];
  f32x4 oacc[8];
#pragma unroll
  for (int j = 0; j < 4; ++j) { m_r[j] = -3.0e38f; l_r[j] = 0.0f; }
#pragma unroll
  for (int i = 0; i < 8; ++i) oacc[i] = (f32x4){0.f, 0.f, 0.f, 0.f};

  const float scale = 0.08838834764831845f;  // 1/sqrt(128)
  const float L2E = 1.4426950408889634f;

  for (int j0 = 0; j0 <= qs; j0 += 64) {
    __syncthreads();
    // stage K tile (source-pre-swizzled so linear gload_lds lands swizzled)
#pragma unroll
    for (int i = 0; i < 4; ++i) {
      int slot = w * 4 + i;
      int r = slot * 4 + (lane >> 4);
      int p = lane & 15;
      int gc = (p & 8) | ((p ^ r) & 7);
      gload_lds16(Kp + (size_t)(j0 + r) * HDd + gc * 8, &Kt[slot * 512]);
    }
    // stage V transposed (reg-staged, swizzled write)
    {
      int r = lane;
#pragma unroll
      for (int i = 0; i < 4; ++i) {
        int c = w * 32 + i * 8;
        bf16x8 vv = *(const bf16x8*)&Vp[(size_t)(j0 + r) * HDd + c];
#pragma unroll
        for (int jj = 0; jj < 8; ++jj) {
          int d = c + jj;
          Vt[d * 64 + (((r >> 3) ^ (d & 7)) * 8) + (r & 7)] = (u16)vv[jj];
        }
      }
    }
    __syncthreads();

    // QK^T: S[16q][64kv] per wave
    f32x4 sacc[4];
#pragma unroll
    for (int nb = 0; nb < 4; ++nb) sacc[nb] = (f32x4){0.f, 0.f, 0.f, 0.f};
#pragma unroll
    for (int kb = 0; kb < 4; ++kb) {
#pragma unroll
      for (int nb = 0; nb < 4; ++nb) {
        int r = nb * 16 + lr;
        int c = kb * 4 + lk;
        int p = (c & 8) | ((c ^ r) & 7);
        bf16x8 kf = *(const bf16x8*)&Kt[r * 128 + p * 8];
        sacc[nb] = __builtin_amdgcn_mfma_f32_16x16x32_bf16(qf[kb], kf, sacc[nb], 0, 0, 0);
      }
    }

    // online softmax; lane's rows are i = lk*4+jj, cols j0 + nb*16 + lr
    float corr[4];
    float pvv[4][4];
#pragma unroll
    for (int jj = 0; jj < 4; ++jj) {
      int qg = qs + w * 16 + lk * 4 + jj;
      float mx = -3.0e38f;
#pragma unroll
      for (int nb = 0; nb < 4; ++nb) {
        float s = sacc[nb][jj] * scale;
        int kg = j0 + nb * 16 + lr;
        s = (kg > qg) ? -3.0e38f : s;
        pvv[jj][nb] = s;
        mx = fmaxf(mx, s);
      }
#pragma unroll
      for (int d = 1; d < 16; d <<= 1) mx = fmaxf(mx, __shfl_xor(mx, d));
      float mnew = fmaxf(m_r[jj], mx);
      corr[jj] = __builtin_amdgcn_exp2f((m_r[jj] - mnew) * L2E);
      float sum = 0.f;
#pragma unroll
      for (int nb = 0; nb < 4; ++nb) {
        float pe = __builtin_amdgcn_exp2f((pvv[jj][nb] - mnew) * L2E);
        pvv[jj][nb] = pe;
        sum += pe;
      }
#pragma unroll
      for (int d = 1; d < 16; d <<= 1) sum += __shfl_xor(sum, d);
      l_r[jj] = l_r[jj] * corr[jj] + sum;
      m_r[jj] = mnew;
    }
#pragma unroll
    for (int nb2 = 0; nb2 < 8; ++nb2)
#pragma unroll
      for (int jj = 0; jj < 4; ++jj) oacc[nb2][jj] *= corr[jj];

    // P -> LDS (wave-local, swizzled), then PV MFMA
#pragma unroll
    for (int jj = 0; jj < 4; ++jj) {
      int i = lk * 4 + jj;
#pragma unroll
      for (int nb = 0; nb < 4; ++nb) {
        int col = nb * 16 + lr;
        int cc = col >> 3;
        Pw[w][i * 64 + ((cc ^ (i & 7)) * 8) + (col & 7)] = f2b(pvv[jj][nb]);
      }
    }
#pragma unroll
    for (int kb2 = 0; kb2 < 2; ++kb2) {
      int c = kb2 * 4 + lk;
      bf16x8 pa = *(const bf16x8*)&Pw[w][lr * 64 + ((c ^ (lr & 7)) * 8)];
#pragma unroll
      for (int nb2 = 0; nb2 < 8; ++nb2) {
        int d = nb2 * 16 + lr;
        bf16x8 vb = *(const bf16x8*)&Vt[d * 64 + ((c ^ (d & 7)) * 8)];
        oacc[nb2] = __builtin_amdgcn_mfma_f32_16x16x32_bf16(pa, vb, oacc[nb2], 0, 0, 0);
      }
    }
  }

  // normalize + store ctx (b, s, h, d) bf16
#pragma unroll
  for (int jj = 0; jj < 4; ++jj) {
    float il = 1.0f / l_r[jj];
    int q = qs + w * 16 + lk * 4 + jj;
    size_t rb = ((size_t)b * Ss + q) * (NHh * HDd) + (size_t)h * HDd;
#pragma unroll
    for (int nb2 = 0; nb2 < 8; ++nb2)
      Ctx[rb + nb2 * 16 + lr] = f2b(oacc[nb2][jj] * il);
  }
}

extern "C" void kernel_launch(void* const* d_in, const int* in_sizes, int n_in,
                              void* d_out, int out_size, void* d_ws, size_t ws_size,
                              hipStream_t stream) {
  const float* hidden = (const float*)d_in[0];
  const float* rope = (const float*)d_in[1];
  // d_in[2] attention_mask: causal triu(k=1), hardcoded in attn_k
  const float* Wqkv = (const float*)d_in[3];
  const float* bqkv = (const float*)d_in[4];
  const float* Wdense = (const float*)d_in[5];
  float* out = (float*)d_out;

  char* w = (char*)d_ws;
  u16* Xbf = (u16*)w;                 // 33.5 MB; reused as ctx after QKV GEMM
  u16* ctx = Xbf;
  w += (size_t)33554432;
  u16* Wq = (u16*)w;                  // 37.7 MB; reused for W_dense bf16 after QKV GEMM
  u16* Wd = Wq;
  w += (size_t)37748736;
  u16* Qb = (u16*)w; w += (size_t)33554432;
  u16* Kb = (u16*)w; w += (size_t)2097152;
  u16* Vb = (u16*)w; w += (size_t)2097152;
  // total ws use: ~104 MB

  // 1. convert hidden + W_qkv to bf16
  cvt_k<<<(16777216 / 4 + 255) / 256, 256, 0, stream>>>(hidden, Xbf, 16777216);
  cvt_k<<<(18874368 / 4 + 255) / 256, 256, 0, stream>>>(Wqkv, Wq, 18874368);
  // 2. QKV GEMM (M=4096, N=4608, K=4096), fused bias + scatter to Q/K/V
  gemm_bt<1><<<dim3(36, 32), 256, 0, stream>>>(Xbf, Wq, 4096, 4608, 4096,
                                               nullptr, bqkv, Qb, Kb, Vb);
  // 3. RoPE in-place on Q and K
  rope_k<<<(Bb * NHh * Ss * 32 + 255) / 256, 256, 0, stream>>>(Qb, rope, NHh);
  rope_k<<<(Bb * KVHh * Ss * 32 + 255) / 256, 256, 0, stream>>>(Kb, rope, KVHh);
  // 4. convert W_dense into Wq's region (dead after step 2)
  cvt_k<<<(16777216 / 4 + 255) / 256, 256, 0, stream>>>(Wdense, Wd, 16777216);
  // 5. flash attention -> ctx (into Xbf's region, dead after step 2)
  attn_k<<<dim3(Ss / 64, NHh, Bb), 256, 0, stream>>>(Qb, Kb, Vb, ctx);
  // 6. dense GEMM -> out (f32)
  gemm_bt<0><<<dim3(32, 32), 256, 0, stream>>>(ctx, Wd, 4096, 4096, 4096,
                                               out, nullptr, nullptr, nullptr, nullptr);
}

// Round 2
// 645.275 us; speedup vs baseline: 1.2252x; 1.2252x over previous
//
#include <hip/hip_runtime.h>
#include <hip/hip_bf16.h>
#include <stdint.h>

#define Bb 2
#define Ss 2048
#define Hh 4096
#define NHh 32
#define HDd 128
#define KVHh 2

typedef __attribute__((ext_vector_type(8))) short bf16x8;
typedef __attribute__((ext_vector_type(4))) float f32x4;
typedef __attribute__((ext_vector_type(16))) float f32x16;
typedef __attribute__((ext_vector_type(4))) unsigned int u32x4;
typedef unsigned short u16;
typedef unsigned int u32;
typedef unsigned long long u64;

__device__ __forceinline__ u16 f2b(float f) {
  union { float f; u32 u; } v; v.f = f;
  u32 r = v.u + 0x7fffu + ((v.u >> 16) & 1u);
  return (u16)(r >> 16);
}
__device__ __forceinline__ float b2f(u16 h) {
  union { u32 u; float f; } v; v.u = ((u32)h) << 16;
  return v.f;
}

__device__ __forceinline__ u32 cvtpk(float lo, float hi_) {
  u32 r;
  asm("v_cvt_pk_bf16_f32 %0, %1, %2" : "=v"(r) : "v"(lo), "v"(hi_));
  return r;
}
__device__ __forceinline__ void plswap(u32& x, u32& y) {
  asm volatile("v_permlane32_swap_b32 %0, %1" : "+v"(x), "+v"(y));
}

// async global->LDS, 16B per lane; LDS dest is wave-uniform base + lane*16
__device__ __forceinline__ void gload_lds16(const u16* g, u16* l) {
  __builtin_amdgcn_global_load_lds(
      (const __attribute__((address_space(1))) u32*)(uintptr_t)g,
      (__attribute__((address_space(3))) u32*)(u32)(uintptr_t)l,
      16, 0, 0);
}

// ---------------- f32 -> bf16 convert (vectorized) ----------------
__global__ void cvt_k(const float* __restrict__ in, u16* __restrict__ out, int n) {
  int i = blockIdx.x * blockDim.x + threadIdx.x;
  int idx = i * 4;
  if (idx >= n) return;
  float4 v = *(const float4*)&in[idx];
  u64 pack = (u64)f2b(v.x) | ((u64)f2b(v.y) << 16) |
             ((u64)f2b(v.z) << 32) | ((u64)f2b(v.w) << 48);
  *(u64*)&out[idx] = pack;
}

// ---------------- RoPE in-place on (B, nheads, S, HD) bf16 ----------------
__global__ void rope_k(u16* __restrict__ X, const float* __restrict__ rope, int nheads) {
  int i = blockIdx.x * blockDim.x + threadIdx.x;
  int p = i & 31;
  int s = (i >> 5) & (Ss - 1);
  int bh = i >> 16;
  if (bh >= Bb * nheads) return;
  int b = bh / nheads;
  size_t base = ((size_t)bh * Ss + s) * HDd + p * 2;
  u32 x01 = *(u32*)&X[base];
  float x0 = b2f((u16)(x01 & 0xffff));
  float x1 = b2f((u16)(x01 >> 16));
  float2 rc = *(const float2*)&rope[(((size_t)b * Ss + s) * 32 + p) * 2];
  float o0 = x0 * rc.x - x1 * rc.y;
  float o1 = x1 * rc.x + x0 * rc.y;
  u32 o = (u32)f2b(o0) | ((u32)f2b(o1) << 16);
  *(u32*)&X[base] = o;
}

// ---------------- 128x128 tile GEMM, C = A * B^T (both K-major) ----------------
template <int EPI>
__global__ void gemm_bt(const u16* __restrict__ A, const u16* __restrict__ Bm,
                        int M, int N, int K,
                        float* __restrict__ Cout, const float* __restrict__ bias,
                        u16* __restrict__ Qb, u16* __restrict__ Kb, u16* __restrict__ Vb) {
  __shared__ u16 As[128 * 32];
  __shared__ u16 Bs[128 * 32];
  const int tid = threadIdx.x;
  const int wave = tid >> 6;
  const int lane = tid & 63;
  const int lr = lane & 15;
  const int lk = lane >> 4;
  const int wr = wave >> 1;
  const int wc = wave & 1;
  const int m0 = blockIdx.y * 128;
  const int n0 = blockIdx.x * 128;
  const int sa_row = lane >> 2;
  const int sa_cb = lane & 3;

  f32x4 acc[4][4];
#pragma unroll
  for (int i = 0; i < 4; ++i)
#pragma unroll
    for (int j = 0; j < 4; ++j) acc[i][j] = (f32x4){0.f, 0.f, 0.f, 0.f};

  for (int k0 = 0; k0 < K; k0 += 32) {
    __syncthreads();
#pragma unroll
    for (int i = 0; i < 2; ++i) {
      int slot = wave * 2 + i;
      int row = slot * 16 + sa_row;
      gload_lds16(A + (size_t)(m0 + row) * K + k0 + sa_cb * 8, &As[slot * 512]);
      gload_lds16(Bm + (size_t)(n0 + row) * K + k0 + sa_cb * 8, &Bs[slot * 512]);
    }
    __syncthreads();
    bf16x8 af[4], bf[4];
#pragma unroll
    for (int mi = 0; mi < 4; ++mi)
      af[mi] = *(const bf16x8*)&As[(wr * 64 + mi * 16 + lr) * 32 + lk * 8];
#pragma unroll
    for (int ni = 0; ni < 4; ++ni)
      bf[ni] = *(const bf16x8*)&Bs[(wc * 64 + ni * 16 + lr) * 32 + lk * 8];
#pragma unroll
    for (int mi = 0; mi < 4; ++mi)
#pragma unroll
      for (int ni = 0; ni < 4; ++ni)
        acc[mi][ni] = __builtin_amdgcn_mfma_f32_16x16x32_bf16(af[mi], bf[ni], acc[mi][ni], 0, 0, 0);
  }

  if constexpr (EPI == 0) {
#pragma unroll
    for (int mi = 0; mi < 4; ++mi)
#pragma unroll
      for (int ni = 0; ni < 4; ++ni) {
        int col = n0 + wc * 64 + ni * 16 + lr;
        int rowb = m0 + wr * 64 + mi * 16 + lk * 4;
#pragma unroll
        for (int j = 0; j < 4; ++j)
          Cout[(size_t)(rowb + j) * N + col] = acc[mi][ni][j];
      }
  } else {
#pragma unroll
    for (int ni = 0; ni < 4; ++ni) {
      int n = n0 + wc * 64 + ni * 16 + lr;
      float bv = bias[n];
#pragma unroll
      for (int mi = 0; mi < 4; ++mi) {
        int mb = m0 + wr * 64 + mi * 16 + lk * 4;
#pragma unroll
        for (int j = 0; j < 4; ++j) {
          int m = mb + j;
          int bb = m >> 11;
          int ss = m & 2047;
          u16 hv = f2b(acc[mi][ni][j] + bv);
          if (n < 4096) {
            Qb[(((size_t)bb * NHh + (n >> 7)) * Ss + ss) * HDd + (n & 127)] = hv;
          } else if (n < 4352) {
            int idx = n - 4096;
            Kb[(((size_t)bb * KVHh + (idx >> 7)) * Ss + ss) * HDd + (idx & 127)] = hv;
          } else {
            int idx = n - 4352;
            Vb[(((size_t)bb * KVHh + (idx >> 7)) * Ss + ss) * HDd + (idx & 127)] = hv;
          }
        }
      }
    }
  }
}

// ---------------- causal GQA flash attention, 8-wave 32x32 swapped-QK^T ----------------
// grid (8, NH, B); 512 threads = 8 waves; wave w owns q rows qs+32w..+32
// S^T = mfma(K,Q): lane owns q = qs+32w+(lane&31); softmax lane-local + 1 permlane-class shfl
// O^T = mfma(V^T,P): same q-per-lane => rescale is lane-scalar
__global__ __launch_bounds__(512, 2) void attn_k(
    const u16* __restrict__ Qb, const u16* __restrict__ Kb,
    const u16* __restrict__ Vb, u16* __restrict__ Ctx) {
  __shared__ u16 Kt[2][64 * 128];   // [kv][d], chunk-swizzle cp=(c&8)|((c^kv)&7), 16B chunks
  __shared__ u16 Vt[2][128 * 64];   // [d][kv] transposed, chunk-swizzle cp=c^(d&7), 8-elem chunks
  const int tid = threadIdx.x;
  const int w = tid >> 6;
  const int lane = tid & 63;
  const int l31 = lane & 31;
  const int hi = lane >> 5;
  const int qt = 7 - (int)blockIdx.x;       // heavy q-tiles first (causal balance)
  const int h = blockIdx.y, b = blockIdx.z;
  const int qs = qt * 256;
  const int qw = qs + w * 32;
  const int hkv = h >> 4;
  const u16* Qp = Qb + ((size_t)(b * NHh + h)) * Ss * HDd;
  const u16* Kp = Kb + ((size_t)(b * KVHh + hkv)) * Ss * HDd;
  const u16* Vp = Vb + ((size_t)(b * KVHh + hkv)) * Ss * HDd;
  const int qrow = qw + l31;

  // Q fragments: Q[qrow][ds*16 + hi*8 .. +8]
  bf16x8 qf[8];
#pragma unroll
  for (int ds = 0; ds < 8; ++ds)
    qf[ds] = *(const bf16x8*)&Qp[(size_t)qrow * HDd + ds * 16 + hi * 8];

  f32x16 accO[4];
#pragma unroll
  for (int i = 0; i < 4; ++i)
#pragma unroll
    for (int r = 0; r < 16; ++r) accO[i][r] = 0.f;
  float m_r = -3.0e38f, l_r = 0.f;

  const float scale = 0.08838834764831845f;
  const float L2E = 1.4426950408889634f;
  const int nt = qs / 64 + 4;

  // ---- prologue: stage tile 0 into buf 0 ----
  {
#pragma unroll
    for (int i = 0; i < 2; ++i) {
      int slot = w * 2 + i;
      int r = slot * 4 + (lane >> 4);
      int p = lane & 15;
      int gc = (p & 8) | ((p ^ r) & 7);
      gload_lds16(Kp + (size_t)r * HDd + gc * 8, &Kt[0][slot * 512]);
    }
    bf16x8 v0 = *(const bf16x8*)&Vp[(size_t)lane * HDd + w * 16];
    bf16x8 v1 = *(const bf16x8*)&Vp[(size_t)lane * HDd + w * 16 + 8];
    u32x4 sv = __builtin_bit_cast(u32x4, (lane & 1) ? v0 : v1);
    u32x4 rv;
    rv.x = __shfl_xor(sv.x, 1); rv.y = __shfl_xor(sv.y, 1);
    rv.z = __shfl_xor(sv.z, 1); rv.w = __shfl_xor(sv.w, 1);
    bf16x8 recv = __builtin_bit_cast(bf16x8, rv);
    int kvp = lane >> 1;
#pragma unroll
    for (int i = 0; i < 8; ++i) {
      int d = w * 16 + (lane & 1) * 8 + i;
      u16 lo = (lane & 1) ? (u16)recv[i] : (u16)v0[i];
      u16 hb = (lane & 1) ? (u16)v1[i] : (u16)recv[i];
      u32 val = (u32)lo | ((u32)hb << 16);
      int cp = (kvp >> 2) ^ (d & 7);
      *(u32*)&Vt[0][d * 64 + cp * 8 + (kvp & 3) * 2] = val;
    }
  }
  __syncthreads();

  for (int t = 0; t < nt; ++t) {
    const int j0 = t * 64;
    const int cur = t & 1;
    const bool havenext = (t + 1 < nt);
    bf16x8 nv0, nv1;
    if (havenext) {
      const int j1 = j0 + 64;
#pragma unroll
      for (int i = 0; i < 2; ++i) {
        int slot = w * 2 + i;
        int r = slot * 4 + (lane >> 4);
        int p = lane & 15;
        int gc = (p & 8) | ((p ^ r) & 7);
        gload_lds16(Kp + (size_t)(j1 + r) * HDd + gc * 8, &Kt[cur ^ 1][slot * 512]);
      }
      nv0 = *(const bf16x8*)&Vp[(size_t)(j1 + lane) * HDd + w * 16];
      nv1 = *(const bf16x8*)&Vp[(size_t)(j1 + lane) * HDd + w * 16 + 8];
    }

    if (j0 <= qw + 31) {
      // ---- QK^T (swapped): accS[kvb] = S^T[kv = j0+32kvb+crow][q = qrow] ----
      f32x16 aS[2];
#pragma unroll
      for (int a = 0; a < 2; ++a)
#pragma unroll
        for (int r = 0; r < 16; ++r) aS[a][r] = 0.f;
#pragma unroll
      for (int kvb = 0; kvb < 2; ++kvb) {
        int r = kvb * 32 + l31;
#pragma unroll
        for (int ds = 0; ds < 8; ++ds) {
          int c = ds * 2 + hi;
          int cp = (c & 8) | ((c ^ r) & 7);
          bf16x8 kf = *(const bf16x8*)&Kt[cur][r * 128 + cp * 8];
          aS[kvb] = __builtin_amdgcn_mfma_f32_32x32x16_bf16(kf, qf[ds], aS[kvb], 0, 0, 0);
        }
      }
      // ---- online softmax (lane-local row) ----
      const bool needmask = (j0 + 63 > qw);
      float mx = -3.0e38f;
#pragma unroll
      for (int a = 0; a < 2; ++a)
#pragma unroll
        for (int r = 0; r < 16; ++r) {
          float s = aS[a][r] * scale;
          if (needmask) {
            int kv = j0 + a * 32 + (r & 3) + 8 * (r >> 2) + 4 * hi;
            s = (kv > qrow) ? -3.0e38f : s;
          }
          aS[a][r] = s;
          mx = fmaxf(mx, s);
        }
      mx = fmaxf(mx, __shfl_xor(mx, 32));
      float mnew = fmaxf(m_r, mx);
      float corr = __builtin_amdgcn_exp2f((m_r - mnew) * L2E);
      float sum = 0.f;
#pragma unroll
      for (int a = 0; a < 2; ++a)
#pragma unroll
        for (int r = 0; r < 16; ++r) {
          float pe = __builtin_amdgcn_exp2f((aS[a][r] - mnew) * L2E);
          aS[a][r] = pe;
          sum += pe;
        }
      sum += __shfl_xor(sum, 32);
      l_r = l_r * corr + sum;
      m_r = mnew;
#pragma unroll
      for (int i = 0; i < 4; ++i)
#pragma unroll
        for (int r = 0; r < 16; ++r) accO[i][r] *= corr;

      // ---- P -> bf16 fragments via cvt_pk + permlane32_swap ----
      u32 cc0[2][4], cc1[2][4];
#pragma unroll
      for (int a = 0; a < 2; ++a)
#pragma unroll
        for (int g = 0; g < 4; ++g) {
          cc0[a][g] = cvtpk(aS[a][g * 4 + 0], aS[a][g * 4 + 1]);
          cc1[a][g] = cvtpk(aS[a][g * 4 + 2], aS[a][g * 4 + 3]);
        }
      bf16x8 pa[4];
#pragma unroll
      for (int ks = 0; ks < 4; ++ks) {
        int a = ks >> 1, g0 = (ks & 1) * 2;
        u32 w0 = cc0[a][g0], w2 = cc0[a][g0 + 1];
        u32 w1 = cc1[a][g0], w3 = cc1[a][g0 + 1];
        plswap(w0, w2);
        plswap(w1, w3);
        u32x4 tv; tv.x = w0; tv.y = w1; tv.z = w2; tv.w = w3;
        pa[ks] = __builtin_bit_cast(bf16x8, tv);
      }
      // ---- PV: accO[dblk] = O^T[d = 32dblk+crow][q = qrow] ----
#pragma unroll
      for (int dblk = 0; dblk < 4; ++dblk) {
        int d = dblk * 32 + l31;
#pragma unroll
        for (int ks = 0; ks < 4; ++ks) {
          int c = ks * 2 + hi;
          int cp = c ^ (d & 7);
          bf16x8 vf = *(const bf16x8*)&Vt[cur][d * 64 + cp * 8];
          accO[dblk] = __builtin_amdgcn_mfma_f32_32x32x16_bf16(vf, pa[ks], accO[dblk], 0, 0, 0);
        }
      }
    }

    if (havenext) {
      u32x4 sv = __builtin_bit_cast(u32x4, (lane & 1) ? nv0 : nv1);
      u32x4 rv;
      rv.x = __shfl_xor(sv.x, 1); rv.y = __shfl_xor(sv.y, 1);
      rv.z = __shfl_xor(sv.z, 1); rv.w = __shfl_xor(sv.w, 1);
      bf16x8 recv = __builtin_bit_cast(bf16x8, rv);
      int kvp = lane >> 1;
#pragma unroll
      for (int i = 0; i < 8; ++i) {
        int d = w * 16 + (lane & 1) * 8 + i;
        u16 lo = (lane & 1) ? (u16)recv[i] : (u16)nv0[i];
        u16 hb = (lane & 1) ? (u16)nv1[i] : (u16)recv[i];
        u32 val = (u32)lo | ((u32)hb << 16);
        int cp = (kvp >> 2) ^ (d & 7);
        *(u32*)&Vt[cur ^ 1][d * 64 + cp * 8 + (kvp & 3) * 2] = val;
      }
    }
    __syncthreads();
  }

  // ---- epilogue: O^T/l -> ctx (b, q, h*128+d) bf16 ----
  {
    float il = 1.0f / l_r;
    size_t rb = ((size_t)b * Ss + qrow) * (size_t)(NHh * HDd) + (size_t)h * HDd;
#pragma unroll
    for (int dblk = 0; dblk < 4; ++dblk)
#pragma unroll
      for (int g = 0; g < 4; ++g) {
        int d0 = dblk * 32 + g * 8 + hi * 4;
        u64 pack = (u64)f2b(accO[dblk][g * 4 + 0] * il) |
                   ((u64)f2b(accO[dblk][g * 4 + 1] * il) << 16) |
                   ((u64)f2b(accO[dblk][g * 4 + 2] * il) << 32) |
                   ((u64)f2b(accO[dblk][g * 4 + 3] * il) << 48);
        *(u64*)&Ctx[rb + d0] = pack;
      }
  }
}

extern "C" void kernel_launch(void* const* d_in, const int* in_sizes, int n_in,
                              void* d_out, int out_size, void* d_ws, size_t ws_size,
                              hipStream_t stream) {
  const float* hidden = (const float*)d_in[0];
  const float* rope = (const float*)d_in[1];
  const float* Wqkv = (const float*)d_in[3];
  const float* bqkv = (const float*)d_in[4];
  const float* Wdense = (const float*)d_in[5];
  float* out = (float*)d_out;

  char* w = (char*)d_ws;
  u16* Xbf = (u16*)w;
  u16* ctx = Xbf;
  w += (size_t)33554432;
  u16* Wq = (u16*)w;
  u16* Wd = Wq;
  w += (size_t)37748736;
  u16* Qb = (u16*)w; w += (size_t)33554432;
  u16* Kb = (u16*)w; w += (size_t)2097152;
  u16* Vb = (u16*)w; w += (size_t)2097152;

  cvt_k<<<(16777216 / 4 + 255) / 256, 256, 0, stream>>>(hidden, Xbf, 16777216);
  cvt_k<<<(18874368 / 4 + 255) / 256, 256, 0, stream>>>(Wqkv, Wq, 18874368);
  gemm_bt<1><<<dim3(36, 32), 256, 0, stream>>>(Xbf, Wq, 4096, 4608, 4096,
                                               nullptr, bqkv, Qb, Kb, Vb);
  rope_k<<<(Bb * NHh * Ss * 32 + 255) / 256, 256, 0, stream>>>(Qb, rope, NHh);
  rope_k<<<(Bb * KVHh * Ss * 32 + 255) / 256, 256, 0, stream>>>(Kb, rope, KVHh);
  cvt_k<<<(16777216 / 4 + 255) / 256, 256, 0, stream>>>(Wdense, Wd, 16777216);
  attn_k<<<dim3(8, NHh, Bb), 512, 0, stream>>>(Qb, Kb, Vb, ctx);
  gemm_bt<0><<<dim3(32, 32), 256, 0, stream>>>(ctx, Wd, 4096, 4096, 4096,
                                               out, nullptr, nullptr, nullptr, nullptr);
}